// Round 13
// baseline (58.401 us; speedup 1.0000x reference)
//
#include <hip/hip_runtime.h>
#include <hip/hip_bf16.h>
#include <math.h>

#define N_STATIONS 276
#define CTX 384
#define TGT 96
#define BATCH 4096
#define NSLOT 4                         // tile-slots per station (striding covers any m)
#define NBLK (N_STATIONS * NSLOT)       // 1104 = 8*138
#define CPX (NBLK / 8)                  // 138 (bijective XCD swizzle)

typedef __attribute__((ext_vector_type(8))) short bf16x8;   // 8 bf16 (4 VGPRs)
typedef __attribute__((ext_vector_type(4))) float f32x4;    // MFMA acc

__device__ __forceinline__ short f2bf(float f) {            // HW RNE cvt
    return (short)__builtin_bit_cast(unsigned short, __float2bfloat16(f));
}
__device__ __forceinline__ float bf2f(short h) {
    unsigned u = ((unsigned)(unsigned short)h) << 16;
    return __builtin_bit_cast(float, u);
}
__device__ __forceinline__ void cvt_hilo(float4 a, float4 b, bf16x8& hi, bf16x8& lo) {
    float f[8] = {a.x, a.y, a.z, a.w, b.x, b.y, b.z, b.w};
#pragma unroll
    for (int i = 0; i < 8; ++i) {
        short h = f2bf(f[i]);
        hi[i] = h;
        lo[i] = f2bf(f[i] - bf2f(h));
    }
}
__device__ __forceinline__ bf16x8 cvt_norm(float4 a, float4 b, float inv, float nb) {
    float f[8] = {a.x, a.y, a.z, a.w, b.x, b.y, b.z, b.w};
    bf16x8 r;
#pragma unroll
    for (int i = 0; i < 8; ++i) r[i] = f2bf(fmaf(f[i], inv, nb));
    return r;
}

// ---------- kernel 1: per-station sample lists (compact) ----------
__global__ __launch_bounds__(1024) void build_lists(
    const int* __restrict__ stations,
    int* __restrict__ order,    // (BATCH,)
    int* __restrict__ offsets)  // (N_STATIONS+1,)
{
    __shared__ int cnt[N_STATIONS];
    __shared__ int cnt2[N_STATIONS];
    __shared__ int poff[N_STATIONS + 1];
    const int tid = threadIdx.x;
    for (int i = tid; i < N_STATIONS; i += 1024) { cnt[i] = 0; cnt2[i] = 0; }
    __syncthreads();
    for (int b = tid; b < BATCH; b += 1024) atomicAdd(&cnt[stations[b]], 1);
    __syncthreads();
    if (tid < 64) {   // wave-parallel inclusive scan, 5 chunks of 64
        int run = 0;
        for (int base = 0; base < N_STATIONS; base += 64) {
            const int i = base + tid;
            int v = (i < N_STATIONS) ? cnt[i] : 0;
#pragma unroll
            for (int off = 1; off < 64; off <<= 1) {
                int u = __shfl_up(v, off, 64);
                if (tid >= off) v += u;
            }
            if (i < N_STATIONS) poff[i + 1] = run + v;
            run += __shfl(v, 63, 64);
        }
        if (tid == 0) poff[0] = 0;
    }
    __syncthreads();
    for (int b = tid; b < BATCH; b += 1024) {
        int s = stations[b];
        int p = atomicAdd(&cnt2[s], 1);
        order[poff[s] + p] = b;          // within-station order irrelevant to outputs
    }
    if (tid <= N_STATIONS) offsets[tid] = poff[tid];
}

// ---------- kernel 2: one wave per (station, tile-slot); all 96 cols per wave ----------
// Per 16-sample tile: z loaded ONCE into 12 bf16 A-frags; 6 n-tiles streamed
// from W (hi/lo split, two independent MFMA chains); direct stores + softplus.
__global__ __launch_bounds__(64, 1) void nlinear_allcols(
    const float* __restrict__ z,        // (BATCH, CTX)
    const int*   __restrict__ order,
    const int*   __restrict__ offsets,
    const float* __restrict__ W,        // (N_STATIONS, TGT, CTX)
    const float* __restrict__ bias,     // (N_STATIONS, TGT)
    const float* __restrict__ loc,
    const float* __restrict__ scale,
    float*       __restrict__ out)      // (BATCH, TGT)
{
    const int bid0 = blockIdx.x;
    const int bid  = (bid0 & 7) * CPX + (bid0 >> 3);   // XCD swizzle (bijective)
    const int s    = bid >> 2;          // station
    const int t0   = bid & 3;           // tile-slot

    const int start = offsets[s];
    const int m     = offsets[s + 1] - start;
    if (t0 * 16 >= m) return;

    const int l  = threadIdx.x;         // 0..63
    const int lr = l & 15;
    const int kh = (l >> 4) * 8;        // k sub-offset within a K=32 step

    const float lc  = loc[s];
    const float sc  = scale[s];
    const float inv = 1.0f / sc;
    const float nb  = -lc * inv;

    const float* wbase = W + (size_t)s * TGT * CTX;
    const int    rbase = (l >> 4) * 4;  // D row base for this lane

    for (int t = t0; t * 16 < m; t += NSLOT) {
        // ---- load this tile's z rows once -> 12 A-frags (48 VGPR) ----
        int j = t * 16 + lr; if (j > m - 1) j = m - 1;
        const float* zr = z + (size_t)order[start + j] * CTX + kh;
        bf16x8 af[12];
#pragma unroll
        for (int kk = 0; kk < 12; ++kk) {
            float4 a0 = *reinterpret_cast<const float4*>(zr + kk * 32);
            float4 a1 = *reinterpret_cast<const float4*>(zr + kk * 32 + 4);
            af[kk] = cvt_norm(a0, a1, inv, nb);
        }

        // sample ids for this lane's 4 D-rows (reused across n-tiles)
        int oid[4]; bool ok[4];
#pragma unroll
        for (int r = 0; r < 4; ++r) {
            const int jj = t * 16 + rbase + r;
            ok[r]  = (jj < m);
            oid[r] = order[start + (ok[r] ? jj : 0)];
        }

        // ---- stream all 6 n-tiles of W through hi/lo MFMA chains ----
        for (int nt = 0; nt < 6; ++nt) {
            const float* wrow = wbase + ((size_t)nt * 16 + lr) * CTX + kh;
            f32x4 ah = {0.f, 0.f, 0.f, 0.f};
            f32x4 al = {0.f, 0.f, 0.f, 0.f};
#pragma unroll
            for (int kk = 0; kk < 12; ++kk) {
                float4 w0 = *reinterpret_cast<const float4*>(wrow + kk * 32);
                float4 w1 = *reinterpret_cast<const float4*>(wrow + kk * 32 + 4);
                bf16x8 bhi, blo;
                cvt_hilo(w0, w1, bhi, blo);
                ah = __builtin_amdgcn_mfma_f32_16x16x32_bf16(af[kk], bhi, ah, 0, 0, 0);
                al = __builtin_amdgcn_mfma_f32_16x16x32_bf16(af[kk], blo, al, 0, 0, 0);
            }
            const float bv = bias[(size_t)s * TGT + nt * 16 + lr];
#pragma unroll
            for (int r = 0; r < 4; ++r) {
                if (ok[r]) {
                    float v = (ah[r] + al[r] + bv) * sc + lc;
                    out[(size_t)oid[r] * TGT + nt * 16 + lr] =
                        fmaxf(v, 0.f) + log1pf(expf(-fabsf(v)));
                }
            }
        }
    }
}

extern "C" void kernel_launch(void* const* d_in, const int* in_sizes, int n_in,
                              void* d_out, int out_size, void* d_ws, size_t ws_size,
                              hipStream_t stream) {
    const float* z        = (const float*)d_in[0];
    const int*   stations = (const int*)  d_in[1];
    const float* W        = (const float*)d_in[2];
    const float* bias     = (const float*)d_in[3];
    const float* loc      = (const float*)d_in[4];
    const float* scale    = (const float*)d_in[5];
    float* out = (float*)d_out;

    int* order   = (int*)d_ws;
    int* offsets = order + BATCH;

    build_lists<<<1, 1024, 0, stream>>>(stations, order, offsets);
    nlinear_allcols<<<NBLK, 64, 0, stream>>>(z, order, offsets, W, bias, loc, scale, out);
}

// Round 14
// 36.090 us; speedup vs baseline: 1.6182x; 1.6182x over previous
//
#include <hip/hip_runtime.h>
#include <hip/hip_bf16.h>
#include <math.h>

#define N_STATIONS 276
#define CTX 384
#define TGT 96
#define BATCH 4096
#define NT_MAX 532          // max possible 16-sample tiles (<= 514 actual)
#define NPANEL 12           // K=384 / 32

typedef __attribute__((ext_vector_type(8))) short bf16x8;   // 8 bf16 (4 VGPRs)
typedef __attribute__((ext_vector_type(4))) float f32x4;    // MFMA acc
typedef const void __attribute__((address_space(1)))* gas_ptr;
typedef void __attribute__((address_space(3)))* las_ptr;

__device__ __forceinline__ short f2bf(float f) {
    return (short)__builtin_bit_cast(unsigned short, __float2bfloat16(f));
}
__device__ __forceinline__ float bf2f(short h) {
    unsigned u = ((unsigned)(unsigned short)h) << 16;
    return __builtin_bit_cast(float, u);
}
__device__ __forceinline__ void cvt_hilo(float4 a, float4 b, bf16x8& hi, bf16x8& lo) {
    float f[8] = {a.x, a.y, a.z, a.w, b.x, b.y, b.z, b.w};
#pragma unroll
    for (int i = 0; i < 8; ++i) {
        short h = f2bf(f[i]);
        hi[i] = h;
        lo[i] = f2bf(f[i] - bf2f(h));
    }
}
__device__ __forceinline__ bf16x8 cvt_norm(float4 a, float4 b, float inv, float nb) {
    float f[8] = {a.x, a.y, a.z, a.w, b.x, b.y, b.z, b.w};
    bf16x8 r;
#pragma unroll
    for (int i = 0; i < 8; ++i) r[i] = f2bf(fmaf(f[i], inv, nb));
    return r;
}

// ---------- kernel 1: per-station lists + 16-sample tile list ----------
// ws layout (ints): [0]=ntiles; [1..533) tiles (s<<16|tt);
//                   [1024..5120) order; [5120..5397) offsets
__global__ __launch_bounds__(1024) void build_lists(
    const int* __restrict__ stations, int* __restrict__ ws)
{
    __shared__ int cnt[N_STATIONS], cnt2[N_STATIONS];
    __shared__ int poff[N_STATIONS + 1], tpoff[N_STATIONS + 1];
    const int tid = threadIdx.x;
    for (int i = tid; i < N_STATIONS; i += 1024) { cnt[i] = 0; cnt2[i] = 0; }
    __syncthreads();
    for (int b = tid; b < BATCH; b += 1024) atomicAdd(&cnt[stations[b]], 1);
    __syncthreads();
    if (tid < 64) {   // dual wave-parallel inclusive scan (samples, tiles)
        int run = 0, trun = 0;
        for (int base = 0; base < N_STATIONS; base += 64) {
            const int i = base + tid;
            int c  = (i < N_STATIONS) ? cnt[i] : 0;
            int v  = c, tv = (c + 15) >> 4;
#pragma unroll
            for (int off = 1; off < 64; off <<= 1) {
                int u  = __shfl_up(v, off, 64);
                int tu = __shfl_up(tv, off, 64);
                if (tid >= off) { v += u; tv += tu; }
            }
            if (i < N_STATIONS) { poff[i + 1] = run + v; tpoff[i + 1] = trun + tv; }
            run  += __shfl(v, 63, 64);
            trun += __shfl(tv, 63, 64);
        }
        if (tid == 0) { poff[0] = 0; tpoff[0] = 0; }
    }
    __syncthreads();
    int* order = ws + 1024;
    for (int b = tid; b < BATCH; b += 1024) {
        int s = stations[b];
        int p = atomicAdd(&cnt2[s], 1);
        order[poff[s] + p] = b;          // within-station order irrelevant to outputs
    }
    for (int i = tid; i < N_STATIONS; i += 1024) {
        int n = (cnt[i] + 15) >> 4, base = tpoff[i];
        for (int t = 0; t < n; ++t) ws[1 + base + t] = (i << 16) | t;
    }
    if (tid <= N_STATIONS) ws[5120 + tid] = poff[tid];
    if (tid == 0) ws[0] = tpoff[N_STATIONS];
}

// ---------- kernel 2: one block (6 waves) per 16-sample tile ----------
// Wave wv computes cols [wv*16, wv*16+16). z A-frags in registers (once).
// W streamed HBM->LDS via global_load_lds in 12 double-buffered 12KB panels
// (96 rows x 32 k-floats). LDS chunk layout XOR-swizzled: slot(row,c) =
// row*8 + (c ^ (row&7)) 16B-chunks -> uniform 8-per-bank on ds_read_b128.
__global__ __launch_bounds__(384, 1) void nlinear_panels(
    const float* __restrict__ z,        // (BATCH, CTX)
    const float* __restrict__ W,        // (N_STATIONS, TGT, CTX)
    const float* __restrict__ bias,     // (N_STATIONS, TGT)
    const float* __restrict__ loc,
    const float* __restrict__ scale,
    const int*   __restrict__ ws,
    float*       __restrict__ out)      // (BATCH, TGT)
{
    __shared__ float lds[2][TGT * 32];   // 2 x 12 KB panels

    const int ntiles = ws[0];
    // m204 bijective XCD swizzle for grid 532 (q=66, r=4)
    const int b0 = blockIdx.x;
    const int xcd = b0 & 7, pos = b0 >> 3;
    const int b = (xcd < 4 ? xcd * 67 : 268 + (xcd - 4) * 66) + pos;
    if (b >= ntiles) return;

    const int* tiles   = ws + 1;
    const int* order   = ws + 1024;
    const int* offsets = ws + 5120;

    const int pk = tiles[b];
    const int s  = pk >> 16;
    const int tt = pk & 0xFFFF;
    const int start = offsets[s];
    const int m     = offsets[s + 1] - start;

    const int tidx = threadIdx.x;
    const int l  = tidx & 63;
    const int wv = tidx >> 6;          // 0..5 = n-tile
    const int lr = l & 15;
    const int kh = (l >> 4) * 8;       // k sub-offset within K=32 step

    const float lc = loc[s], sc = scale[s];
    const float inv = 1.0f / sc, nb = -lc * inv;

    // ---- z A-frags: loaded once, 48 VGPR ----
    int j = tt * 16 + lr; if (j > m - 1) j = m - 1;
    const float* zr = z + (size_t)order[start + j] * CTX + kh;
    bf16x8 af[NPANEL];
#pragma unroll
    for (int kk = 0; kk < NPANEL; ++kk) {
        float4 a0 = *(const float4*)(zr + kk * 32);
        float4 a1 = *(const float4*)(zr + kk * 32 + 4);
        af[kk] = cvt_norm(a0, a1, inv, nb);
    }

    // ---- store ids (D row = sample) ----
    const int rbase = (l >> 4) * 4;
    int oid[4]; bool ok[4];
#pragma unroll
    for (int r = 0; r < 4; ++r) {
        int jj = tt * 16 + rbase + r;
        ok[r]  = (jj < m);
        oid[r] = order[start + (ok[r] ? jj : 0)];
    }
    const float bv = bias[(size_t)s * TGT + wv * 16 + lr];

    // ---- DMA source setup: 2 calls/wave/panel; call jc covers rows
    //      [(wv*2+jc)*8, +8) x 8 chunks, source chunk pre-XOR-swizzled ----
    const float* Wb = W + (size_t)s * TGT * CTX;
    const float* src[2]; int ldsoff[2];
#pragma unroll
    for (int jc = 0; jc < 2; ++jc) {
        const int q   = (wv * 2 + jc) * 64 + l;     // chunk slot this lane fills
        const int rw  = q >> 3;                     // W row
        const int scn = (q & 7) ^ (rw & 7);         // logical source chunk
        src[jc]    = Wb + (size_t)rw * CTX + scn * 4;
        ldsoff[jc] = (wv * 2 + jc) * 256;           // float idx of wave-uniform base
    }

    // prologue: panels 0 and 1 in flight
#pragma unroll
    for (int jc = 0; jc < 2; ++jc)
        __builtin_amdgcn_global_load_lds((gas_ptr)(src[jc]), (las_ptr)&lds[0][ldsoff[jc]], 16, 0, 0);
#pragma unroll
    for (int jc = 0; jc < 2; ++jc)
        __builtin_amdgcn_global_load_lds((gas_ptr)(src[jc] + 32), (las_ptr)&lds[1][ldsoff[jc]], 16, 0, 0);
    __syncthreads();   // compiler drain -> p0 (and p1) resident

    // LDS read slots for this lane (fixed across panels)
    const int row = wv * 16 + lr;
    const int c0  = kh >> 2;                        // in {0,2,4,6}
    const int s0  = row * 8 + (c0 ^ (row & 7));
    const int s1  = row * 8 + ((c0 + 1) ^ (row & 7));

    f32x4 ah = {0.f,0.f,0.f,0.f}, al = {0.f,0.f,0.f,0.f};
    for (int kk = 0; kk < NPANEL; ++kk) {
        const float* buf = lds[kk & 1];
        float4 a0 = *(const float4*)(buf + s0 * 4);
        float4 a1 = *(const float4*)(buf + s1 * 4);
        bf16x8 bhi, blo;
        cvt_hilo(a0, a1, bhi, blo);
        ah = __builtin_amdgcn_mfma_f32_16x16x32_bf16(af[kk], bhi, ah, 0, 0, 0);
        al = __builtin_amdgcn_mfma_f32_16x16x32_bf16(af[kk], blo, al, 0, 0, 0);
        __syncthreads();   // (1) all waves done reading buf; (2) drain -> p_{kk+1} resident
        if (kk < NPANEL - 2) {
#pragma unroll
            for (int jc = 0; jc < 2; ++jc)
                __builtin_amdgcn_global_load_lds((gas_ptr)(src[jc] + (kk + 2) * 32),
                                                 (las_ptr)&lds[kk & 1][ldsoff[jc]], 16, 0, 0);
        }
    }

    // ---- epilogue: bias + denorm + softplus ----
#pragma unroll
    for (int r = 0; r < 4; ++r) {
        if (ok[r]) {
            float v = (ah[r] + al[r] + bv) * sc + lc;
            out[(size_t)oid[r] * TGT + wv * 16 + lr] =
                fmaxf(v, 0.f) + log1pf(expf(-fabsf(v)));
        }
    }
}

extern "C" void kernel_launch(void* const* d_in, const int* in_sizes, int n_in,
                              void* d_out, int out_size, void* d_ws, size_t ws_size,
                              hipStream_t stream) {
    const float* z        = (const float*)d_in[0];
    const int*   stations = (const int*)  d_in[1];
    const float* W        = (const float*)d_in[2];
    const float* bias     = (const float*)d_in[3];
    const float* loc      = (const float*)d_in[4];
    const float* scale    = (const float*)d_in[5];
    float* out = (float*)d_out;
    int* ws = (int*)d_ws;

    build_lists<<<1, 1024, 0, stream>>>(stations, ws);
    nlinear_panels<<<NT_MAX, 384, 0, stream>>>(z, W, bias, loc, scale, ws, out);
}